// Round 8
// baseline (103.246 us; speedup 1.0000x reference)
//
#include <hip/hip_runtime.h>
#include <math.h>

#define CEPS 1e-9f

typedef _Float16 half8 __attribute__((ext_vector_type(8)));
typedef _Float16 h2 __attribute__((ext_vector_type(2)));
typedef __fp16 fp16x2 __attribute__((ext_vector_type(2)));
typedef float floatx16 __attribute__((ext_vector_type(16)));

// x  : [4,56,56,8,32] fp32    W: [4,4,128,32] fp32    bias: [128] fp32
// out: [4,112,112,128] fp32 act
//
// R20: split-region transpose overlap. History:
//  R12: 75us latency-bound. R13/14/16: all (256,6) tries spilled -> abandoned,
//       (256,5) is the proven spill-free cap. R15: 61.4us. R18: ILP-2, 60.6us,
//       VALU busy-time pinned ~37us => issue-bound.
//  R19: routing re-layout lane=(pl,c,e), all-DPP reduces (bits 0..3), votes
//       in registers: caps_mfma dropped below the 42us harness memsets
//       (bench 119->102). LDS 32768 (5 blocks/CU, structural: softmax couples
//       all 8 c; pixel-split forces a 5th reduce bit off DPP range).
//  R20: vote transpose split by K-half: half-1 votes (ca 0..63) written to
//       the LDS region ABOVE xt right after half-1's pack -> the 32 b16
//       writes retire under half-2 MFMAs; barrier moves to just before
//       half-2's writes (ca 64..127 overlay dead xt). pf liveness halves
//       (-16 peak regs). Routing base = select(c<4). Numerics bit-identical.
//  LDS map: bytes 0..15999 xt (phase1) then scxHi (ca 64..127);
//           bytes 16384..32767 scxLo (ca 0..63). Region = [w][pl][i][ca64].

template<int CTRL>
__device__ __forceinline__ float dpp_add(float v) {
    return v + __int_as_float(__builtin_amdgcn_update_dpp(
        0, __float_as_int(v), CTRL, 0xF, 0xF, false));
}
__device__ __forceinline__ h2 pkrtz(float a, float b) {
    return __builtin_bit_cast(h2, __builtin_amdgcn_cvt_pkrtz(a, b));
}
__device__ __forceinline__ float fdot2(h2 a, h2 b, float c) {
    return __builtin_amdgcn_fdot2(__builtin_bit_cast(fp16x2, a),
                                  __builtin_bit_cast(fp16x2, b), c, false);
}

// B[k][n] fragment table: idx = ((parity*8 + s)*4 + t)*64 + l -> 8 f16
__global__ __launch_bounds__(256) void prep_w(const float* __restrict__ Wt,
                                              _Float16* __restrict__ wb) {
    int idx = blockIdx.x * 256 + threadIdx.x;    // [0, 8192)
    int parity = idx >> 11;
    int s = (idx >> 8) & 7;
    int t = (idx >> 6) & 3;
    int l = idx & 63;
    int rh = parity >> 1, rw = parity & 1;
    int n = t * 32 + (l & 31);
    int h = l >> 5;
    int ci0 = ((s & 1) << 4) + (h << 3);
    int kh = ((s >> 2) << 1) + 1 - rh;
    int kw = (((s >> 1) & 1) << 1) + 1 - rw;
    const float* src = Wt + (((kh * 4 + kw) * 128 + n) << 5) + ci0;
    float4 w0 = *(const float4*)src;
    float4 w1 = *(const float4*)(src + 4);
    half8 hv;
    hv[0] = (_Float16)w0.x; hv[1] = (_Float16)w0.y;
    hv[2] = (_Float16)w0.z; hv[3] = (_Float16)w0.w;
    hv[4] = (_Float16)w1.x; hv[5] = (_Float16)w1.y;
    hv[6] = (_Float16)w1.z; hv[7] = (_Float16)w1.w;
    *(half8*)(wb + ((long)idx << 3)) = hv;
}

__global__ __launch_bounds__(256, 5) void caps_mfma(
    const float* __restrict__ x,
    const _Float16* __restrict__ wb,
    const float* __restrict__ bias,
    float* __restrict__ out)
{
    __shared__ __align__(16) unsigned char smem[32768];
    _Float16* xt = (_Float16*)smem;          // bytes 0..15999 (phase 1)
    _Float16* smem16 = (_Float16*)smem;

    const int tid = threadIdx.x;
    const int tile = blockIdx.x;            // 0..195 : 14x14 tiles of 4x4 pixels
    const int tu = tile / 14, tv = tile - tu * 14;
    const int u0 = tu * 4, v0 = tv * 4;
    const int rh = blockIdx.y >> 1;         // p & 1
    const int rw = blockIdx.y & 1;          // q & 1
    const int bp = blockIdx.z;              // b'
    const _Float16* wsrc = wb + ((long)blockIdx.y << 14);   // parity slice, 16 KB

    // ---- stage x: fp32 -> f16 tile [ri(5)][rj(5)][i(8)][ci padded 40] ----
    #pragma unroll
    for (int it = 0; it < 4; ++it) {
        int idx = tid + (it << 8);
        if (idx < 800) {
            int cell = idx >> 5;            // 0..24
            int r = idx & 31;
            int i = r >> 2;
            int ci0 = (r & 3) << 3;
            int ri = cell / 5, rj = cell - ri * 5;
            int gi = u0 + rh - 1 + ri;
            int gj = v0 + rw - 1 + rj;
            float tmp[8] = {0.f, 0.f, 0.f, 0.f, 0.f, 0.f, 0.f, 0.f};
            if ((unsigned)gi < 56u && (unsigned)gj < 56u) {
                const float* src = x + (((i & 3) * 56 + gi) * 56 + gj) * 256
                                     + ((bp * 2 + (i >> 2)) << 5) + ci0;
                float4 a0 = *(const float4*)src;
                float4 a1 = *(const float4*)(src + 4);
                tmp[0] = a0.x; tmp[1] = a0.y; tmp[2] = a0.z; tmp[3] = a0.w;
                tmp[4] = a1.x; tmp[5] = a1.y; tmp[6] = a1.z; tmp[7] = a1.w;
            }
            half8 hv;
            #pragma unroll
            for (int j = 0; j < 8; ++j) hv[j] = (_Float16)tmp[j];
            *(half8*)(xt + (cell * 8 + i) * 40 + ci0) = hv;
        }
    }
    __syncthreads();

    const int l = tid & 63;
    const int w = tid >> 6;                 // wave = u-row within tile
    const int col = l & 31, h = l >> 5;
    const int invA = (l & 31) * 40 + (h << 3);

    // routing lane mapping (used for bias hoist + routing)
    const int e = l & 1;
    const int c = (l >> 1) & 7;
    const int pl = l >> 4;

    // bias hoisted: global latency hides under the K-loop MFMAs
    h2 bq[4];
    {
        const float* bpt = bias + (c << 4) + (e << 3);
        float4 b0 = *(const float4*)bpt;
        float4 b1 = *(const float4*)(bpt + 4);
        bq[0] = pkrtz(b0.x, b0.y); bq[1] = pkrtz(b0.z, b0.w);
        bq[2] = pkrtz(b1.x, b1.y); bq[3] = pkrtz(b1.z, b1.w);
    }

    // ---- MFMA K-loop, TWO passes of 2 n-tiles; per-half pack AND per-half
    //      LDS write (split regions). acc = 32 AGPR; pf live = 16 regs max.
    #pragma unroll
    for (int hf = 0; hf < 2; ++hf) {
        floatx16 acc0, acc1;
        #pragma unroll
        for (int j = 0; j < 16; ++j) { acc0[j] = 0.f; acc1[j] = 0.f; }
        const int tb = hf << 1;
        #pragma unroll
        for (int s = 0; s < 8; ++s) {
            const int tkh = s >> 2;
            const int tkw = (s >> 1) & 1;
            const int row = w + 1 - tkh;
            int aoff = (row * 5 + 1 - tkw) * 320 + ((s & 1) << 4) + invA;
            // SPILL FIX (R14): opaque A-frag address prevents cross-half CSE
            // of the 8 identical xt loads (R13: +32 live VGPR -> spill).
            asm("" : "+v"(aoff));
            half8 af = *(const half8*)(xt + aoff);
            half8 bf0 = *(const half8*)(wsrc + (((s * 4 + tb) * 64 + l) << 3));
            half8 bf1 = *(const half8*)(wsrc + (((s * 4 + tb + 1) * 64 + l) << 3));
            acc0 = __builtin_amdgcn_mfma_f32_32x32x16_f16(af, bf0, acc0, 0, 0, 0);
            acc1 = __builtin_amdgcn_mfma_f32_32x32x16_f16(af, bf1, acc1, 0, 0, 0);
        }
        // half 0 -> Lo region (bytes 16384+, disjoint from xt: NO barrier,
        //   writes retire under half-1's... under the next half's MFMAs).
        // half 1 -> barrier first (xt now dead), then Hi region over xt.
        if (hf == 1) __syncthreads();
        _Float16* dst = smem16 + (hf ? 0 : 8192) + w * 2048;
        #pragma unroll
        for (int m = 0; m < 8; ++m) {
            h2 q0 = pkrtz(acc0[2 * m], acc0[2 * m + 1]);   // tt = 0
            h2 q1 = pkrtz(acc1[2 * m], acc1[2 * m + 1]);   // tt = 1
            const int mpl = m >> 1;
            const int il0 = (2 * m) & 3;
            const int il1 = (2 * m + 1) & 3;
            const int r0 = (mpl * 8 + 4 * h + il0) * 64 + col;
            const int r1 = (mpl * 8 + 4 * h + il1) * 64 + col;
            dst[r0]      = q0[0];
            dst[r1]      = q0[1];
            dst[r0 + 32] = q1[0];
            dst[r1 + 32] = q1[1];
        }
        __builtin_amdgcn_sched_barrier(0);
    }
    // wave-local RAW through LDS below: per-wave in-order DS, no barrier.

    // ---- routing: lane = (pl, c, e); region select by c<4 ----
    const _Float16* rp = smem16 + (c < 4 ? 8192 : 0) + w * 2048
                       + (pl << 9) + ((c & 3) << 4) + (e << 3);

    // all 8 i-votes for my 8 atoms, in registers: 8x ds_read_b128
    h2 va[8][4];
    #pragma unroll
    for (int i = 0; i < 8; ++i) {
        half8 vv = *(const half8*)(rp + (i << 6));
        va[i][0][0] = vv[0]; va[i][0][1] = vv[1];
        va[i][1][0] = vv[2]; va[i][1][1] = vv[3];
        va[i][2][0] = vv[4]; va[i][2][1] = vv[5];
        va[i][3][0] = vv[6]; va[i][3][1] = vv[7];
    }

    const h2 c0125 = pkrtz(0.125f, 0.125f);

    h2 pre[4];
    float lgv[8];

    // ---- round 0: route = 1/8; i-sum = local pk_add tree ----
    #pragma unroll
    for (int d = 0; d < 4; ++d) {
        h2 s01 = va[0][d] + va[1][d];
        h2 s23 = va[2][d] + va[3][d];
        h2 s45 = va[4][d] + va[5][d];
        h2 s67 = va[6][d] + va[7][d];
        h2 s = (s01 + s23) + (s45 + s67);
        pre[d] = s * c0125 + bq[d];
    }
    {
        float n = fdot2(pre[0], pre[0], 0.f);
        n = fdot2(pre[1], pre[1], n);
        n = fdot2(pre[2], pre[2], n);
        n = fdot2(pre[3], pre[3], n);
        float nq = dpp_add<0xB1>(n);          // + e-partner -> full 16-atom norm
        float sc = nq * __builtin_amdgcn_rcpf(1.f + nq)
                      * __builtin_amdgcn_rsqf(nq + CEPS);
        h2 sc2 = pkrtz(sc, sc);
        #pragma unroll
        for (int d = 0; d < 4; ++d) pre[d] *= sc2;      // pre = act
    }
    #pragma unroll
    for (int i = 0; i < 8; ++i) {
        float p = fdot2(va[i][0], pre[0], 0.f);
        p = fdot2(va[i][1], pre[1], p);
        p = fdot2(va[i][2], pre[2], p);
        p = fdot2(va[i][3], pre[3], p);
        lgv[i] = dpp_add<0xB1>(p);            // full 16-atom dot, per i
    }

    // ---- rounds 1,2 ----
    #pragma unroll
    for (int r = 1; r < 3; ++r) {
        // softmax over c (lane bits 1..3): xor2 / xor4 / xor8, all DPP.
        h2 rt2[8];
        #pragma unroll
        for (int i = 0; i < 8; ++i) {
            float ee = __expf(lgv[i]);
            float ss = dpp_add<0x4E>(ee);     // quad_perm xor2 : c^1
            ss = dpp_add<0x141>(ss);          // row_half_mirror == xor4 : c^2
            ss = dpp_add<0x128>(ss);          // row ror8 == xor8 : c^4
            float route = ee * __builtin_amdgcn_rcpf(ss);
            rt2[i] = pkrtz(route, route);
        }
        #pragma unroll
        for (int d = 0; d < 4; ++d) {
            h2 p0 = rt2[0] * va[0][d], p1 = rt2[1] * va[1][d];
            h2 p2 = rt2[2] * va[2][d], p3 = rt2[3] * va[3][d];
            h2 p4 = rt2[4] * va[4][d], p5 = rt2[5] * va[5][d];
            h2 p6 = rt2[6] * va[6][d], p7 = rt2[7] * va[7][d];
            h2 s = ((p0 + p1) + (p2 + p3)) + ((p4 + p5) + (p6 + p7));
            pre[d] = s + bq[d];
        }
        {
            float n = fdot2(pre[0], pre[0], 0.f);
            n = fdot2(pre[1], pre[1], n);
            n = fdot2(pre[2], pre[2], n);
            n = fdot2(pre[3], pre[3], n);
            float nq = dpp_add<0xB1>(n);
            float sc = nq * __builtin_amdgcn_rcpf(1.f + nq)
                          * __builtin_amdgcn_rsqf(nq + CEPS);
            h2 sc2 = pkrtz(sc, sc);
            #pragma unroll
            for (int d = 0; d < 4; ++d) pre[d] *= sc2;  // act
        }
        if (r < 2) {
            #pragma unroll
            for (int i = 0; i < 8; ++i) {
                float p = fdot2(va[i][0], pre[0], 0.f);
                p = fdot2(va[i][1], pre[1], p);
                p = fdot2(va[i][2], pre[2], p);
                p = fdot2(va[i][3], pre[3], p);
                lgv[i] += dpp_add<0xB1>(p);
            }
        }
    }

    // ---- store: every lane writes its 8 atoms = 2x float4, coalesced ----
    {
        const int p = ((u0 + w) << 1) + rh;
        const int q = ((v0 + pl) << 1) + rw;
        float* op = out + (((bp * 112 + p) * 112 + q) << 7) + (c << 4) + (e << 3);
        float4 o0 = make_float4((float)pre[0][0], (float)pre[0][1],
                                (float)pre[1][0], (float)pre[1][1]);
        float4 o1 = make_float4((float)pre[2][0], (float)pre[2][1],
                                (float)pre[3][0], (float)pre[3][1]);
        *(float4*)op = o0;
        *(float4*)(op + 4) = o1;
    }
}

extern "C" void kernel_launch(void* const* d_in, const int* in_sizes, int n_in,
                              void* d_out, int out_size, void* d_ws, size_t ws_size,
                              hipStream_t stream) {
    const float* x  = (const float*)d_in[0];
    const float* Wt = (const float*)d_in[1];
    const float* b  = (const float*)d_in[2];
    float* out = (float*)d_out;
    _Float16* wb = (_Float16*)d_ws;          // 4 parities x 16384 f16 = 64 KB

    prep_w<<<32, 256, 0, stream>>>(Wt, wb);
    dim3 grid(196, 4, 4);    // 14x14 4x4-pixel tiles, 4 parity classes, 4 b'
    caps_mfma<<<grid, 256, 0, stream>>>(x, wb, b, out);
}